// Round 1
// baseline (668.851 us; speedup 1.0000x reference)
//
#include <hip/hip_runtime.h>

#define TOKS 49
#define NHEADS 8

typedef _Float16 f16;
typedef _Float16 f16x4 __attribute__((ext_vector_type(4)));
typedef _Float16 f16x8 __attribute__((ext_vector_type(8)));
typedef float f32x4 __attribute__((ext_vector_type(4)));

// workspace byte offsets
#define WS_BIAS   0          // 8*49*49 f32 = 76832 B
#define WS_QKVWT  77824      // 768*256 f16 = 393216 B
#define WS_PROJWT 471040     // 256*256 f16 = 131072 B
#define WS_ATTNOUT 602112    // B*49*256 f16

// ---------------- CPB bias table ----------------
__global__ __launch_bounds__(256) void cpb_bias_kernel(
    const float* __restrict__ w1, const float* __restrict__ b1,
    const float* __restrict__ w2, float* __restrict__ bias_ws)
{
    __shared__ float tbl[169][8];
    int t = threadIdx.x;
    if (t < 169) {
        int i = t / 13, j = t % 13;
        float t0 = 8.0f * (float)(i - 6) / 6.0f;
        float t1 = 8.0f * (float)(j - 6) / 6.0f;
        const float invlog8 = 0.4808983469629878f;   // 1/ln(8)
        t0 = copysignf(log1pf(fabsf(t0)) * invlog8, t0);
        t1 = copysignf(log1pf(fabsf(t1)) * invlog8, t1);
        float acc[8] = {0.f,0.f,0.f,0.f,0.f,0.f,0.f,0.f};
        for (int u = 0; u < 512; ++u) {
            float pre = t0 * w1[u] + t1 * w1[512 + u] + b1[u];
            float g = 0.5f * pre * (1.0f + erff(pre * 0.70710678118654752f));
#pragma unroll
            for (int h = 0; h < 8; ++h) acc[h] += g * w2[u * 8 + h];
        }
#pragma unroll
        for (int h = 0; h < 8; ++h) tbl[t][h] = acc[h];
    }
    __syncthreads();
    for (int idx = t; idx < 8 * 49 * 49; idx += 256) {
        int h = idx / 2401, rem = idx % 2401;
        int n = rem / 49, m = rem % 49;
        int dh = n / 7 - m / 7 + 6;
        int dw = n % 7 - m % 7 + 6;
        float v = tbl[dh * 13 + dw][h];
        bias_ws[idx] = 16.0f / (1.0f + expf(-v));
    }
}

// ---------------- weight transpose + f16 convert ----------------
__global__ __launch_bounds__(256) void wconv_kernel(
    const float* __restrict__ qkv_w, const float* __restrict__ proj_w,
    f16* __restrict__ qkv_wT, f16* __restrict__ proj_wT)
{
    int idx = blockIdx.x * 256 + threadIdx.x;
    if (idx < 768 * 256) {
        int n = idx >> 8, k = idx & 255;
        qkv_wT[idx] = (f16)qkv_w[k * 768 + n];
    }
    if (idx < 256 * 256) {
        int n = idx >> 8, k = idx & 255;
        proj_wT[idx] = (f16)proj_w[k * 256 + n];
    }
}

// ---------------- fused qkv + window attention ----------------
// grid = B*4 : block handles (window b, head-pair hp). 256 threads = 4 waves.
__global__ __launch_bounds__(256) void win_attn_kernel(
    const float* __restrict__ x, const float* __restrict__ qkv_b,
    const float* __restrict__ logit_scale, const f16* __restrict__ qkv_wT,
    const float* __restrict__ bias_ws, f16* __restrict__ attn_out)
{
    __shared__ alignas(16) f16 xs[64][264];      // x window, f16 (also reused as P buffer)
    __shared__ alignas(16) f16 qs[2][64][40];    // q (later normalized)
    __shared__ alignas(16) f16 kq[2][64][40];    // k (later normalized)
    __shared__ alignas(16) f16 vT[2][32][72];    // v transposed [d][token]

    const int tid  = threadIdx.x;
    const int lane = tid & 63;
    const int w    = tid >> 6;
    const int b    = blockIdx.x >> 2;
    const int hp   = blockIdx.x & 3;
    const int l15  = lane & 15;
    const int lq   = lane >> 4;

    // phase 1: stage x -> LDS f16, zero-pad rows 49..63
    {
        const float* xb = x + (size_t)b * (49 * 256);
#pragma unroll
        for (int i = 0; i < 16; ++i) {
            int r = i * 4 + w;
            int c = lane * 4;
            float4 v = make_float4(0.f, 0.f, 0.f, 0.f);
            if (r < 49) v = *(const float4*)(xb + r * 256 + c);
            f16x4 hv; hv[0]=(f16)v.x; hv[1]=(f16)v.y; hv[2]=(f16)v.z; hv[3]=(f16)v.w;
            *(f16x4*)(&xs[r][c]) = hv;
        }
    }
    __syncthreads();

    const int hl   = w >> 1;          // local head (0/1)
    const int head = hp * 2 + hl;     // global head
    const int dhalf = (w & 1) * 16;

    // phase 2: qkv GEMM (64x32 slice per wave per chunk), chunks: q,k,v
    {
#pragma unroll
        for (int ci = 0; ci < 3; ++ci) {
            const int cg   = ci * 256 + head * 32 + dhalf; // global qkv col base
            const int bcol = cg + l15;
            const f16* bp = qkv_wT + (size_t)bcol * 256 + lq * 8;
            f16x8 bfrag[8];
#pragma unroll
            for (int ks = 0; ks < 8; ++ks) bfrag[ks] = *(const f16x8*)(bp + ks * 32);
            f32x4 acc[4];
#pragma unroll
            for (int mt = 0; mt < 4; ++mt) { acc[mt][0]=0.f; acc[mt][1]=0.f; acc[mt][2]=0.f; acc[mt][3]=0.f; }
#pragma unroll
            for (int ks = 0; ks < 8; ++ks) {
#pragma unroll
                for (int mt = 0; mt < 4; ++mt) {
                    f16x8 af = *(const f16x8*)(&xs[mt * 16 + l15][ks * 32 + lq * 8]);
                    acc[mt] = __builtin_amdgcn_mfma_f32_16x16x32_f16(af, bfrag[ks], acc[mt], 0, 0, 0);
                }
            }
            float bv = qkv_b[bcol];
            int d = dhalf + l15;
#pragma unroll
            for (int mt = 0; mt < 4; ++mt) {
#pragma unroll
                for (int j = 0; j < 4; ++j) {
                    int row = mt * 16 + lq * 4 + j;
                    f16 hv = (f16)(acc[mt][j] + bv);
                    if (ci == 0)      qs[hl][row][d] = hv;
                    else if (ci == 1) kq[hl][row][d] = hv;
                    else              vT[hl][d][row] = hv;
                }
            }
        }
    }
    __syncthreads();

    // phase 3: L2-normalize q,k rows (256 tasks = 2 mats x 2 heads x 64 rows)
    {
        int isK = tid >> 7;
        int h2  = (tid >> 6) & 1;
        int row = tid & 63;
        f16* rowp = isK ? &kq[h2][row][0] : &qs[h2][row][0];
        float ss = 0.f;
#pragma unroll
        for (int d2 = 0; d2 < 32; ++d2) { float v = (float)rowp[d2]; ss += v * v; }
        float rs = rsqrtf(fmaxf(ss, 1e-20f));
#pragma unroll
        for (int d2 = 0; d2 < 32; ++d2) rowp[d2] = (f16)((float)rowp[d2] * rs);
    }
    __syncthreads();

    // phase 4: attention. wave -> (head hl, row-half mh)
    const int mh = w & 1;
    float sc = logit_scale[head];
    sc = __expf(fminf(fmaxf(sc, -100.f), 4.605170185988091f)); // exp(clip(ls, -100, ln100))
    const float* biash = bias_ws + head * 2401;

    f32x4 sacc[2][4];
#pragma unroll
    for (int a = 0; a < 2; ++a)
#pragma unroll
        for (int c = 0; c < 4; ++c) { sacc[a][c][0]=0.f; sacc[a][c][1]=0.f; sacc[a][c][2]=0.f; sacc[a][c][3]=0.f; }

#pragma unroll
    for (int mtl = 0; mtl < 2; ++mtl) {
        int mt = mh * 2 + mtl;
        f16x8 qf = *(const f16x8*)(&qs[hl][mt * 16 + l15][lq * 8]);
#pragma unroll
        for (int nt = 0; nt < 4; ++nt) {
            f16x8 kf = *(const f16x8*)(&kq[hl][nt * 16 + l15][lq * 8]);
            sacc[mtl][nt] = __builtin_amdgcn_mfma_f32_16x16x32_f16(qf, kf, sacc[mtl][nt], 0, 0, 0);
        }
    }

    // softmax (rows of this wave's half), write P into ps (overlay on xs)
    f16 (*ps)[72] = reinterpret_cast<f16(*)[72]>(&xs[0][0]) + hl * 64;
#pragma unroll
    for (int mtl = 0; mtl < 2; ++mtl) {
#pragma unroll
        for (int j = 0; j < 4; ++j) {
            int row = (mh * 2 + mtl) * 16 + lq * 4 + j;
            float tv[4];
#pragma unroll
            for (int nt = 0; nt < 4; ++nt) {
                int col = nt * 16 + l15;
                float s = sacc[mtl][nt][j] * sc;
                tv[nt] = (col < 49) ? (s + ((row < 49) ? biash[row * 49 + col] : 0.f)) : -1e30f;
            }
            float mx = fmaxf(fmaxf(tv[0], tv[1]), fmaxf(tv[2], tv[3]));
#pragma unroll
            for (int off = 1; off < 16; off <<= 1) mx = fmaxf(mx, __shfl_xor(mx, off, 64));
            float p[4], sum = 0.f;
#pragma unroll
            for (int nt = 0; nt < 4; ++nt) { p[nt] = __expf(tv[nt] - mx); sum += p[nt]; }
#pragma unroll
            for (int off = 1; off < 16; off <<= 1) sum += __shfl_xor(sum, off, 64);
            float inv = 1.0f / sum;
#pragma unroll
            for (int nt = 0; nt < 4; ++nt) ps[row][nt * 16 + l15] = (f16)(p[nt] * inv);
        }
    }
    __syncthreads();

    // PV: out(64x32) = P(64x64) @ V(64x32)
    f32x4 oacc[2][2];
#pragma unroll
    for (int a = 0; a < 2; ++a)
#pragma unroll
        for (int c = 0; c < 2; ++c) { oacc[a][c][0]=0.f; oacc[a][c][1]=0.f; oacc[a][c][2]=0.f; oacc[a][c][3]=0.f; }

#pragma unroll
    for (int mtl = 0; mtl < 2; ++mtl) {
        int mt = mh * 2 + mtl;
#pragma unroll
        for (int kb = 0; kb < 2; ++kb) {
            f16x8 pf = *(const f16x8*)(&ps[mt * 16 + l15][kb * 32 + lq * 8]);
#pragma unroll
            for (int nt = 0; nt < 2; ++nt) {
                f16x8 vf = *(const f16x8*)(&vT[hl][nt * 16 + l15][kb * 32 + lq * 8]);
                oacc[mtl][nt] = __builtin_amdgcn_mfma_f32_16x16x32_f16(pf, vf, oacc[mtl][nt], 0, 0, 0);
            }
        }
    }
#pragma unroll
    for (int mtl = 0; mtl < 2; ++mtl) {
#pragma unroll
        for (int j = 0; j < 4; ++j) {
            int row = (mh * 2 + mtl) * 16 + lq * 4 + j;
            if (row < 49) {
#pragma unroll
                for (int nt = 0; nt < 2; ++nt) {
                    attn_out[((size_t)(b * 49 + row)) * 256 + head * 32 + nt * 16 + l15] =
                        (f16)oacc[mtl][nt][j];
                }
            }
        }
    }
}

// ---------------- output projection GEMM ----------------
__global__ __launch_bounds__(256) void proj_kernel(
    const f16* __restrict__ attn_out, const f16* __restrict__ proj_wT,
    const float* __restrict__ proj_b, float* __restrict__ out, int Mtot)
{
    __shared__ alignas(16) f16 as[64][264];
    const int tid = threadIdx.x;
    const int lane = tid & 63;
    const int w = tid >> 6;
    const int mb = blockIdx.x >> 2;
    const int nb = blockIdx.x & 3;
    const int l15 = lane & 15, lq = lane >> 4;

#pragma unroll
    for (int i = 0; i < 8; ++i) {
        int r = i * 8 + (tid >> 5);
        int c = (tid & 31) * 8;
        int gr = mb * 64 + r;
        f16x8 v;
        if (gr < Mtot) v = *(const f16x8*)(attn_out + (size_t)gr * 256 + c);
        else { v[0]=(f16)0.f;v[1]=(f16)0.f;v[2]=(f16)0.f;v[3]=(f16)0.f;v[4]=(f16)0.f;v[5]=(f16)0.f;v[6]=(f16)0.f;v[7]=(f16)0.f; }
        *(f16x8*)(&as[r][c]) = v;
    }
    __syncthreads();

    const int mq = w >> 1, nq = w & 1;
    f32x4 acc[2][2];
#pragma unroll
    for (int a = 0; a < 2; ++a)
#pragma unroll
        for (int c = 0; c < 2; ++c) { acc[a][c][0]=0.f; acc[a][c][1]=0.f; acc[a][c][2]=0.f; acc[a][c][3]=0.f; }

    f16x8 bfrag[8][2];
#pragma unroll
    for (int nt = 0; nt < 2; ++nt) {
        int col = nb * 64 + nq * 32 + nt * 16 + l15;
        const f16* bp = proj_wT + (size_t)col * 256 + lq * 8;
#pragma unroll
        for (int ks = 0; ks < 8; ++ks) bfrag[ks][nt] = *(const f16x8*)(bp + ks * 32);
    }
#pragma unroll
    for (int ks = 0; ks < 8; ++ks) {
#pragma unroll
        for (int mtl = 0; mtl < 2; ++mtl) {
            f16x8 af = *(const f16x8*)(&as[(mq * 2 + mtl) * 16 + l15][ks * 32 + lq * 8]);
#pragma unroll
            for (int nt = 0; nt < 2; ++nt)
                acc[mtl][nt] = __builtin_amdgcn_mfma_f32_16x16x32_f16(af, bfrag[ks][nt], acc[mtl][nt], 0, 0, 0);
        }
    }
#pragma unroll
    for (int mtl = 0; mtl < 2; ++mtl) {
#pragma unroll
        for (int j = 0; j < 4; ++j) {
            int row = (mq * 2 + mtl) * 16 + lq * 4 + j;
            int gr = mb * 64 + row;
            if (gr < Mtot) {
#pragma unroll
                for (int nt = 0; nt < 2; ++nt) {
                    int col = nb * 64 + nq * 32 + nt * 16 + l15;
                    out[(size_t)gr * 256 + col] = acc[mtl][nt][j] + proj_b[col];
                }
            }
        }
    }
}

extern "C" void kernel_launch(void* const* d_in, const int* in_sizes, int n_in,
                              void* d_out, int out_size, void* d_ws, size_t ws_size,
                              hipStream_t stream) {
    const float* x           = (const float*)d_in[0];
    const float* qkv_w       = (const float*)d_in[1];
    const float* qkv_b       = (const float*)d_in[2];
    const float* proj_w      = (const float*)d_in[3];
    const float* proj_b      = (const float*)d_in[4];
    const float* logit_scale = (const float*)d_in[5];
    const float* cpb_w1      = (const float*)d_in[6];
    const float* cpb_b1      = (const float*)d_in[7];
    const float* cpb_w2      = (const float*)d_in[8];
    float* out = (float*)d_out;

    const int B = in_sizes[0] / (49 * 256);
    char* ws = (char*)d_ws;
    float* bias_ws = (float*)(ws + WS_BIAS);
    f16* qkv_wT    = (f16*)(ws + WS_QKVWT);
    f16* proj_wT   = (f16*)(ws + WS_PROJWT);
    f16* attn_out  = (f16*)(ws + WS_ATTNOUT);

    hipLaunchKernelGGL(cpb_bias_kernel, dim3(1), dim3(256), 0, stream,
                       cpb_w1, cpb_b1, cpb_w2, bias_ws);
    hipLaunchKernelGGL(wconv_kernel, dim3(1024), dim3(256), 0, stream,
                       qkv_w, proj_w, qkv_wT, proj_wT);
    hipLaunchKernelGGL(win_attn_kernel, dim3(B * 4), dim3(256), 0, stream,
                       x, qkv_b, logit_scale, qkv_wT, bias_ws, attn_out);
    const int Mtot = B * 49;
    const int mblocks = (Mtot + 63) / 64;
    hipLaunchKernelGGL(proj_kernel, dim3(mblocks * 4), dim3(256), 0, stream,
                       attn_out, proj_wT, proj_b, out, Mtot);
}

// Round 2
// 390.988 us; speedup vs baseline: 1.7107x; 1.7107x over previous
//
#include <hip/hip_runtime.h>

typedef _Float16 f16;
typedef _Float16 f16x4 __attribute__((ext_vector_type(4)));
typedef _Float16 f16x8 __attribute__((ext_vector_type(8)));
typedef float f32x4 __attribute__((ext_vector_type(4)));

// workspace byte offsets
#define WS_BIAS    0          // 8*64*64 f32 = 131072
#define WS_TBL     131072     // 169*8 f32 = 5408
#define WS_QKVWT   136704     // 768*256 f16 = 393216
#define WS_PROJWT  529920     // 256*256 f16 = 131072
#define WS_ATTNOUT 660992     // B*49*256 f16

// ---------------- CPB MLP: one block per table entry ----------------
__global__ __launch_bounds__(512) void cpb_mlp_kernel(
    const float* __restrict__ w1, const float* __restrict__ b1,
    const float* __restrict__ w2, float* __restrict__ tbl)
{
    const int bid = blockIdx.x;            // 0..168
    const int i = bid / 13, j = bid % 13;
    float t0 = 8.0f * (float)(i - 6) / 6.0f;
    float t1 = 8.0f * (float)(j - 6) / 6.0f;
    const float invlog8 = 0.4808983469629878f;
    t0 = copysignf(log1pf(fabsf(t0)) * invlog8, t0);
    t1 = copysignf(log1pf(fabsf(t1)) * invlog8, t1);

    const int t = threadIdx.x;             // 0..511 = hidden unit
    float pre = t0 * w1[t] + t1 * w1[512 + t] + b1[t];
    float g = 0.5f * pre * (1.0f + erff(pre * 0.70710678118654752f));
    float a[8];
#pragma unroll
    for (int h = 0; h < 8; ++h) a[h] = g * w2[t * 8 + h];
#pragma unroll
    for (int off = 1; off < 64; off <<= 1)
#pragma unroll
        for (int h = 0; h < 8; ++h) a[h] += __shfl_xor(a[h], off, 64);

    __shared__ float wred[8][8];
    const int w = t >> 6, lane = t & 63;
    if (lane == 0)
#pragma unroll
        for (int h = 0; h < 8; ++h) wred[w][h] = a[h];
    __syncthreads();
    if (t < 8) {
        float s = 0.f;
#pragma unroll
        for (int ww = 0; ww < 8; ++ww) s += wred[ww][t];
        tbl[bid * 8 + t] = s;
    }
}

// ---------------- scatter bias table -> padded [8][64][64] ----------------
__global__ __launch_bounds__(256) void cpb_bias_kernel(
    const float* __restrict__ tbl, float* __restrict__ bias_ws)
{
    int idx = blockIdx.x * 256 + threadIdx.x;   // h*4096 + r*64 + c
    int h = idx >> 12, r = (idx >> 6) & 63, c = idx & 63;
    float v = 0.f;
    if (r < 49 && c < 49) {
        int dh = r / 7 - c / 7 + 6;
        int dw = r % 7 - c % 7 + 6;
        float bv = tbl[(dh * 13 + dw) * 8 + h];
        v = 16.0f / (1.0f + __expf(-bv));
    }
    bias_ws[idx] = v;
}

// ---------------- weight transpose via LDS tiles ----------------
__global__ __launch_bounds__(256) void wconv_kernel(
    const float* __restrict__ qkv_w, const float* __restrict__ proj_w,
    f16* __restrict__ qkv_wT, f16* __restrict__ proj_wT)
{
    __shared__ float ts[64][65];
    int b = blockIdx.x;
    const float* src; f16* dst; int W, kb, nb;
    if (b < 48) { src = qkv_w;  dst = qkv_wT;  W = 768; kb = b / 12; nb = b % 12; }
    else { b -= 48; src = proj_w; dst = proj_wT; W = 256; kb = b / 4;  nb = b % 4; }
    const int t = threadIdx.x;
#pragma unroll
    for (int it = 0; it < 4; ++it) {
        int k = it * 16 + (t >> 4);
        int n4 = (t & 15) * 4;
        float4 v = *(const float4*)(src + (size_t)(kb * 64 + k) * W + nb * 64 + n4);
        ts[k][n4] = v.x; ts[k][n4 + 1] = v.y; ts[k][n4 + 2] = v.z; ts[k][n4 + 3] = v.w;
    }
    __syncthreads();
#pragma unroll
    for (int it = 0; it < 4; ++it) {
        int n = it * 16 + (t >> 4);
        int k4 = (t & 15) * 4;
        f16x4 hv;
        hv[0] = (f16)ts[k4][n]; hv[1] = (f16)ts[k4 + 1][n];
        hv[2] = (f16)ts[k4 + 2][n]; hv[3] = (f16)ts[k4 + 3][n];
        *(f16x4*)(dst + (size_t)(nb * 64 + n) * 256 + kb * 64 + k4) = hv;
    }
}

// ---------------- fused qkv + window attention ----------------
// block = (window b, head-pair hp); 256 thr = 4 waves; 48 KB LDS -> 3 blocks/CU
__global__ __launch_bounds__(256, 3) void win_attn_kernel(
    const float* __restrict__ x, const float* __restrict__ qkv_b,
    const float* __restrict__ logit_scale, const f16* __restrict__ qkv_wT,
    const float* __restrict__ bias_ws, f16* __restrict__ attn_out, int nwg)
{
    __shared__ alignas(16) char smem0[18432];    // xs [64][136] (17408 B) / ps [128][72] (18432 B)
    __shared__ alignas(16) f16 qs[2][64][40];    // stride 40 f16 = 20 banks (2-way tile)
    __shared__ alignas(16) f16 kq[2][64][40];
    __shared__ alignas(16) f16 vT[2][32][72];    // stride 72 f16 = 4-bank spacing
    __shared__ float invq_s[2][64];
    __shared__ float invk_s[2][64];
    f16 (*xs)[136] = reinterpret_cast<f16(*)[136]>(smem0);
    f16 (*ps)[72]  = reinterpret_cast<f16(*)[72]>(smem0);

    // XCD swizzle: keep the 4 head-pair blocks of a window on one XCD
    const int orig = blockIdx.x;
    const int wg = ((nwg & 7) == 0) ? ((orig & 7) * (nwg >> 3) + (orig >> 3)) : orig;
    const int b  = wg >> 2;
    const int hp = wg & 3;

    const int tid = threadIdx.x;
    const int lane = tid & 63;
    const int w = tid >> 6;
    const int l15 = lane & 15, lq = lane >> 4;
    const int hl = w >> 1;               // local head 0/1
    const int dh = w & 1;                // d-half
    const int head = hp * 2 + hl;

    const float* xb = x + (size_t)b * (49 * 256);
    const int srow = tid >> 5;           // 0..7
    const int scol = (tid & 31) * 4;     // 0..124

    // ---- stage half 0 (cols 0..127)
    float4 sreg[8];
#pragma unroll
    for (int i = 0; i < 8; ++i) {
        int r = i * 8 + srow;
        sreg[i] = (r < 49) ? *(const float4*)(xb + r * 256 + scol) : make_float4(0.f, 0.f, 0.f, 0.f);
    }
#pragma unroll
    for (int i = 0; i < 8; ++i) {
        int r = i * 8 + srow;
        f16x4 hv; hv[0] = (f16)sreg[i].x; hv[1] = (f16)sreg[i].y; hv[2] = (f16)sreg[i].z; hv[3] = (f16)sreg[i].w;
        *(f16x4*)(&xs[r][scol]) = hv;
    }
    __syncthreads();

    // ---- issue half-1 loads (overlap with half-0 compute)
#pragma unroll
    for (int i = 0; i < 8; ++i) {
        int r = i * 8 + srow;
        sreg[i] = (r < 49) ? *(const float4*)(xb + r * 256 + 128 + scol) : make_float4(0.f, 0.f, 0.f, 0.f);
    }

    f32x4 acc[3][4];
#pragma unroll
    for (int ci = 0; ci < 3; ++ci)
#pragma unroll
        for (int mt = 0; mt < 4; ++mt) { acc[ci][mt][0] = 0.f; acc[ci][mt][1] = 0.f; acc[ci][mt][2] = 0.f; acc[ci][mt][3] = 0.f; }

    const int bcol = head * 32 + dh * 16 + l15;

    // ---- compute half 0
#pragma unroll
    for (int ks = 0; ks < 4; ++ks) {
        f16x8 af[4];
#pragma unroll
        for (int mt = 0; mt < 4; ++mt) af[mt] = *(const f16x8*)(&xs[mt * 16 + l15][ks * 32 + lq * 8]);
#pragma unroll
        for (int ci = 0; ci < 3; ++ci) {
            f16x8 bf = *(const f16x8*)(qkv_wT + (size_t)(ci * 256 + bcol) * 256 + ks * 32 + lq * 8);
#pragma unroll
            for (int mt = 0; mt < 4; ++mt)
                acc[ci][mt] = __builtin_amdgcn_mfma_f32_16x16x32_f16(af[mt], bf, acc[ci][mt], 0, 0, 0);
        }
    }
    __syncthreads();

    // ---- write half 1 to LDS
#pragma unroll
    for (int i = 0; i < 8; ++i) {
        int r = i * 8 + srow;
        f16x4 hv; hv[0] = (f16)sreg[i].x; hv[1] = (f16)sreg[i].y; hv[2] = (f16)sreg[i].z; hv[3] = (f16)sreg[i].w;
        *(f16x4*)(&xs[r][scol]) = hv;
    }
    __syncthreads();

    // ---- compute half 1
#pragma unroll
    for (int ks = 0; ks < 4; ++ks) {
        f16x8 af[4];
#pragma unroll
        for (int mt = 0; mt < 4; ++mt) af[mt] = *(const f16x8*)(&xs[mt * 16 + l15][ks * 32 + lq * 8]);
#pragma unroll
        for (int ci = 0; ci < 3; ++ci) {
            f16x8 bf = *(const f16x8*)(qkv_wT + (size_t)(ci * 256 + bcol) * 256 + 128 + ks * 32 + lq * 8);
#pragma unroll
            for (int mt = 0; mt < 4; ++mt)
                acc[ci][mt] = __builtin_amdgcn_mfma_f32_16x16x32_f16(af[mt], bf, acc[ci][mt], 0, 0, 0);
        }
    }

    // ---- epilogue: q/k/v to LDS (unnormalized)
    {
        float bq = qkv_b[bcol], bk = qkv_b[256 + bcol], bv = qkv_b[512 + bcol];
        const int d = dh * 16 + l15;
#pragma unroll
        for (int mt = 0; mt < 4; ++mt)
#pragma unroll
            for (int j = 0; j < 4; ++j) {
                int row = mt * 16 + lq * 4 + j;
                qs[hl][row][d] = (f16)(acc[0][mt][j] + bq);
                kq[hl][row][d] = (f16)(acc[1][mt][j] + bk);
                vT[hl][d][row] = (f16)(acc[2][mt][j] + bv);
            }
    }
    __syncthreads();

    // ---- norms (read-only, vectorized); fold logit scale into invq
    {
        const int isK = tid >> 7;
        const int h2 = (tid >> 6) & 1;
        const int row = tid & 63;
        const f16* rp = isK ? &kq[h2][row][0] : &qs[h2][row][0];
        float ss = 0.f;
#pragma unroll
        for (int c8 = 0; c8 < 4; ++c8) {
            f16x8 v = *(const f16x8*)(rp + c8 * 8);
#pragma unroll
            for (int e = 0; e < 8; ++e) { float f = (float)v[e]; ss += f * f; }
        }
        float inv = rsqrtf(fmaxf(ss, 1e-20f));
        if (isK) invk_s[h2][row] = inv;
        else {
            float sc = __expf(fminf(logit_scale[hp * 2 + h2], 4.605170185988091f));
            invq_s[h2][row] = inv * sc;
        }
    }
    __syncthreads();

    // ---- QK^T (wave -> head hl, row-half mh)
    const int mh = w & 1;
    f32x4 sacc[2][4];
#pragma unroll
    for (int a = 0; a < 2; ++a)
#pragma unroll
        for (int c = 0; c < 4; ++c) { sacc[a][c][0] = 0.f; sacc[a][c][1] = 0.f; sacc[a][c][2] = 0.f; sacc[a][c][3] = 0.f; }
#pragma unroll
    for (int mtl = 0; mtl < 2; ++mtl) {
        int mt = mh * 2 + mtl;
        f16x8 qf = *(const f16x8*)(&qs[hl][mt * 16 + l15][lq * 8]);
#pragma unroll
        for (int nt = 0; nt < 4; ++nt) {
            f16x8 kf = *(const f16x8*)(&kq[hl][nt * 16 + l15][lq * 8]);
            sacc[mtl][nt] = __builtin_amdgcn_mfma_f32_16x16x32_f16(qf, kf, sacc[mtl][nt], 0, 0, 0);
        }
    }

    // ---- softmax with cosine norms + bias; P -> ps (overlays dead xs)
    const float* biash = bias_ws + head * 4096;
#pragma unroll
    for (int mtl = 0; mtl < 2; ++mtl) {
#pragma unroll
        for (int j = 0; j < 4; ++j) {
            int row = (mh * 2 + mtl) * 16 + lq * 4 + j;
            float iq = invq_s[hl][row];
            float tv[4];
#pragma unroll
            for (int nt = 0; nt < 4; ++nt) {
                int col = nt * 16 + l15;
                float sv = sacc[mtl][nt][j] * iq * invk_s[hl][col] + biash[row * 64 + col];
                tv[nt] = (col < 49) ? sv : -1e30f;
            }
            float mx = fmaxf(fmaxf(tv[0], tv[1]), fmaxf(tv[2], tv[3]));
#pragma unroll
            for (int off = 1; off < 16; off <<= 1) mx = fmaxf(mx, __shfl_xor(mx, off, 64));
            float p[4], sum = 0.f;
#pragma unroll
            for (int nt = 0; nt < 4; ++nt) { p[nt] = __expf(tv[nt] - mx); sum += p[nt]; }
#pragma unroll
            for (int off = 1; off < 16; off <<= 1) sum += __shfl_xor(sum, off, 64);
            float invsum = 1.0f / sum;
#pragma unroll
            for (int nt = 0; nt < 4; ++nt) ps[hl * 64 + row][nt * 16 + l15] = (f16)(p[nt] * invsum);
        }
    }
    // same wave wrote these P rows -> no barrier needed before PV

    // ---- PV
    f32x4 oacc[2][2];
#pragma unroll
    for (int a = 0; a < 2; ++a)
#pragma unroll
        for (int c = 0; c < 2; ++c) { oacc[a][c][0] = 0.f; oacc[a][c][1] = 0.f; oacc[a][c][2] = 0.f; oacc[a][c][3] = 0.f; }
#pragma unroll
    for (int mtl = 0; mtl < 2; ++mtl) {
        int mt = mh * 2 + mtl;
#pragma unroll
        for (int kb = 0; kb < 2; ++kb) {
            f16x8 pf = *(const f16x8*)(&ps[hl * 64 + mt * 16 + l15][kb * 32 + lq * 8]);
#pragma unroll
            for (int nt = 0; nt < 2; ++nt) {
                f16x8 vf = *(const f16x8*)(&vT[hl][nt * 16 + l15][kb * 32 + lq * 8]);
                oacc[mtl][nt] = __builtin_amdgcn_mfma_f32_16x16x32_f16(pf, vf, oacc[mtl][nt], 0, 0, 0);
            }
        }
    }
#pragma unroll
    for (int mtl = 0; mtl < 2; ++mtl)
#pragma unroll
        for (int j = 0; j < 4; ++j) {
            int row = (mh * 2 + mtl) * 16 + lq * 4 + j;
            if (row < 49) {
#pragma unroll
                for (int nt = 0; nt < 2; ++nt)
                    attn_out[((size_t)(b * 49 + row)) * 256 + head * 32 + nt * 16 + l15] = (f16)oacc[mtl][nt][j];
            }
        }
}

// ---------------- output projection: block = 64 x 256 ----------------
__global__ __launch_bounds__(256, 4) void proj_kernel(
    const f16* __restrict__ attn_out, const f16* __restrict__ proj_wT,
    const float* __restrict__ proj_b, float* __restrict__ out, int Mtot)
{
    __shared__ alignas(16) f16 as[64][264];   // stride 264 f16 = 4-bank spacing
    const int tid = threadIdx.x, lane = tid & 63, w = tid >> 6;
    const int l15 = lane & 15, lq = lane >> 4;
    const int mb = blockIdx.x;

#pragma unroll
    for (int i = 0; i < 8; ++i) {
        int r = i * 8 + (tid >> 5);
        int c = (tid & 31) * 8;
        int gr = mb * 64 + r;
        f16x8 v = {};
        if (gr < Mtot) v = *(const f16x8*)(attn_out + (size_t)gr * 256 + c);
        *(f16x8*)(&as[r][c]) = v;
    }
    __syncthreads();

    f32x4 acc[4][4];
#pragma unroll
    for (int a = 0; a < 4; ++a)
#pragma unroll
        for (int c = 0; c < 4; ++c) { acc[a][c][0] = 0.f; acc[a][c][1] = 0.f; acc[a][c][2] = 0.f; acc[a][c][3] = 0.f; }

    const f16* bbase = proj_wT + (size_t)(w * 64) * 256;
#pragma unroll
    for (int ks = 0; ks < 8; ++ks) {
        f16x8 af[4], bf[4];
#pragma unroll
        for (int mt = 0; mt < 4; ++mt) af[mt] = *(const f16x8*)(&as[mt * 16 + l15][ks * 32 + lq * 8]);
#pragma unroll
        for (int nt = 0; nt < 4; ++nt) bf[nt] = *(const f16x8*)(bbase + (size_t)(nt * 16 + l15) * 256 + ks * 32 + lq * 8);
#pragma unroll
        for (int mt = 0; mt < 4; ++mt)
#pragma unroll
            for (int nt = 0; nt < 4; ++nt)
                acc[mt][nt] = __builtin_amdgcn_mfma_f32_16x16x32_f16(af[mt], bf[nt], acc[mt][nt], 0, 0, 0);
    }
    float pb[4];
#pragma unroll
    for (int nt = 0; nt < 4; ++nt) pb[nt] = proj_b[w * 64 + nt * 16 + l15];
#pragma unroll
    for (int mt = 0; mt < 4; ++mt)
#pragma unroll
        for (int j = 0; j < 4; ++j) {
            int gr = mb * 64 + mt * 16 + lq * 4 + j;
            if (gr < Mtot) {
#pragma unroll
                for (int nt = 0; nt < 4; ++nt)
                    out[(size_t)gr * 256 + w * 64 + nt * 16 + l15] = acc[mt][nt][j] + pb[nt];
            }
        }
}

extern "C" void kernel_launch(void* const* d_in, const int* in_sizes, int n_in,
                              void* d_out, int out_size, void* d_ws, size_t ws_size,
                              hipStream_t stream) {
    const float* x           = (const float*)d_in[0];
    const float* qkv_w       = (const float*)d_in[1];
    const float* qkv_b       = (const float*)d_in[2];
    const float* proj_w      = (const float*)d_in[3];
    const float* proj_b      = (const float*)d_in[4];
    const float* logit_scale = (const float*)d_in[5];
    const float* cpb_w1      = (const float*)d_in[6];
    const float* cpb_b1      = (const float*)d_in[7];
    const float* cpb_w2      = (const float*)d_in[8];
    float* out = (float*)d_out;

    const int B = in_sizes[0] / (49 * 256);
    char* ws = (char*)d_ws;
    float* bias_ws = (float*)(ws + WS_BIAS);
    float* tbl_ws  = (float*)(ws + WS_TBL);
    f16* qkv_wT    = (f16*)(ws + WS_QKVWT);
    f16* proj_wT   = (f16*)(ws + WS_PROJWT);
    f16* attn_out  = (f16*)(ws + WS_ATTNOUT);

    hipLaunchKernelGGL(cpb_mlp_kernel, dim3(169), dim3(512), 0, stream, cpb_w1, cpb_b1, cpb_w2, tbl_ws);
    hipLaunchKernelGGL(cpb_bias_kernel, dim3(128), dim3(256), 0, stream, tbl_ws, bias_ws);
    hipLaunchKernelGGL(wconv_kernel, dim3(64), dim3(256), 0, stream, qkv_w, proj_w, qkv_wT, proj_wT);

    const int nwg = B * 4;
    hipLaunchKernelGGL(win_attn_kernel, dim3(nwg), dim3(256), 0, stream,
                       x, qkv_b, logit_scale, qkv_wT, bias_ws, attn_out, nwg);

    const int Mtot = B * 49;
    const int mblocks = (Mtot + 63) / 64;
    hipLaunchKernelGGL(proj_kernel, dim3(mblocks), dim3(256), 0, stream,
                       attn_out, proj_wT, proj_b, out, Mtot);
}